// Round 7
// baseline (444.388 us; speedup 1.0000x reference)
//
#include <hip/hip_runtime.h>
#include <cstdint>
#include <cstddef>

// FiBiNET fused inference — MFMA bf16, chained-layout, perm-packed A-frags.
// B=16384, F=26, D=16, P=325 pairs, hidden 64->32->1.
// se_p = (A_i*A_j) * p  =>  y1 += u@w1a + (c*u)@w1b,  u = (e_i@W_p) .* e_j.
// t^T = W_p^T @ e_i^T (16x16x32, K zero-padded in wcat) lands each lane at
// the A-operand slot of the y-MFMA (m=lane&15=batch, k'=2d+{u,cu}=q*8+j).
// R7: 1024-thr k_main blocks (16 waves, 4/SIMD — latency hiding 2x) and
// coalesced LDS-transpose weight repack.
// eS indices in USHORT units: field f at f*16 (32 B). Row stride 424 ush.

#define F_FIELDS 26
#define P_PAIRS 325
#define BATCH 16384
#define BN_EPS 1e-3f

typedef short bf16x8 __attribute__((ext_vector_type(8)));
typedef float f32x4 __attribute__((ext_vector_type(4)));

struct PairTab { unsigned char iu[P_PAIRS]; unsigned char ju[P_PAIRS]; };
static constexpr PairTab make_pairs() {
    PairTab t{};
    int p = 0;
    for (int a = 0; a < F_FIELDS; ++a)
        for (int b = a + 1; b < F_FIELDS; ++b) { t.iu[p] = (unsigned char)a; t.ju[p] = (unsigned char)b; ++p; }
    return t;
}
__constant__ PairTab PT = make_pairs();
// 16 chunks of ~20 pairs
__constant__ int CHUNK[17] = {0,21,41,61,82,102,122,142,163,183,203,223,244,264,284,304,325};

// float -> bf16 RNE (off the hot path)
__device__ __forceinline__ unsigned short bf16u(float v) {
    unsigned u = __float_as_uint(v);
    unsigned r = (u + 0x7fffu + ((u >> 16) & 1u)) >> 16;
    return (unsigned short)r;
}
__device__ __forceinline__ unsigned pk_bf16(float lo, float hi) {
    return (unsigned)bf16u(lo) | ((unsigned)bf16u(hi) << 16);
}
__device__ __forceinline__ float bflo(unsigned d) { return __uint_as_float(d << 16); }
__device__ __forceinline__ float bfhi(unsigned d) { return __uint_as_float(d & 0xffff0000u); }
// truncating pack: dst = (hi16(cu) << 16) | hi16(u)  — one v_perm_b32
__device__ __forceinline__ unsigned pk_trunc(float u, float cu) {
    return __builtin_amdgcn_perm(__float_as_uint(cu), __float_as_uint(u), 0x07060302u);
}

// ---------------- K1: merged prep ----------------
// blocks 0..255: gather embeddings (bf16) + SE attention.
// blocks 256..580: per-pair coalesced weight repack via LDS transpose:
//   w1cat [325][64 o][32 k'], k'=2d+su: su=0 -> w1[p*16+d][o], su=1 -> w1[5200+p*16+d][o]
//   wcat  [325][16 dout][32 din] = W_p^T, din 16..31 zeroed.
__global__ __launch_bounds__(256) void k_prep(const int* __restrict__ x,
        const float* __restrict__ emb, const float* __restrict__ sw1,
        const float* __restrict__ sw2, const float* __restrict__ w1,
        const float* __restrict__ blw, unsigned short* __restrict__ eG,
        float* __restrict__ aG, unsigned short* __restrict__ w1cat,
        unsigned short* __restrict__ wcat) {
    const int tid = threadIdx.x;
    if (blockIdx.x >= 256) {
        const int p = blockIdx.x - 256;
        __shared__ float wu[1024], wv[1024], wb[256];
        // coalesced loads: rows p*16..p*16+15 are 1024 contiguous floats
        ((float4*)wu)[tid] = ((const float4*)(w1 + (size_t)p * 1024))[tid];
        ((float4*)wv)[tid] = ((const float4*)(w1 + 332800 + (size_t)p * 1024))[tid];
        if (tid < 64) ((float4*)wb)[tid] = ((const float4*)(blw + (size_t)p * 256))[tid];
        __syncthreads();
        {   // w1cat: 2048 ush, thread t writes 8 contiguous
            int base = tid * 8;
            int o = base >> 5, k0 = base & 31;
            unsigned short outv[8];
            #pragma unroll
            for (int j = 0; j < 8; ++j) {
                int k = k0 + j, d = k >> 1, su = k & 1;
                outv[j] = bf16u(su ? wv[d * 64 + o] : wu[d * 64 + o]);
            }
            *(int4*)(w1cat + (size_t)p * 2048 + base) = *(const int4*)outv;
        }
        if (tid < 64) {  // wcat: 512 ush, thread t writes 8 contiguous
            int base = tid * 8;
            int dout = base >> 5, din0 = base & 31;
            unsigned short outv[8];
            #pragma unroll
            for (int j = 0; j < 8; ++j) {
                int din = din0 + j;
                outv[j] = (din < 16) ? bf16u(wb[din * 16 + dout]) : (unsigned short)0;
            }
            *(int4*)(wcat + (size_t)p * 512 + base) = *(const int4*)outv;
        }
        return;
    }
    __shared__ float z_s[64][F_FIELDS];
    __shared__ float sw1_s[F_FIELDS * 13];
    __shared__ float sw2_s[13 * F_FIELDS];
    const int b0 = blockIdx.x * 64;
    for (int i = tid; i < F_FIELDS * 13; i += 256) { sw1_s[i] = sw1[i]; sw2_s[i] = sw2[i]; }
    for (int idx = tid; idx < 64 * F_FIELDS; idx += 256) {
        int r = idx / F_FIELDS;
        int f = idx - r * F_FIELDS;
        int b = b0 + r;
        int id = x[b * F_FIELDS + f] + f * 1000;
        const float4* src = (const float4*)(emb + (size_t)id * 16);
        float4 v0 = src[0], v1 = src[1], v2 = src[2], v3 = src[3];
        int4 o0, o1;
        o0.x = (int)pk_bf16(v0.x, v0.y); o0.y = (int)pk_bf16(v0.z, v0.w);
        o0.z = (int)pk_bf16(v1.x, v1.y); o0.w = (int)pk_bf16(v1.z, v1.w);
        o1.x = (int)pk_bf16(v2.x, v2.y); o1.y = (int)pk_bf16(v2.z, v2.w);
        o1.z = (int)pk_bf16(v3.x, v3.y); o1.w = (int)pk_bf16(v3.z, v3.w);
        int4* dst = (int4*)(eG + ((size_t)b * F_FIELDS + f) * 16);
        dst[0] = o0; dst[1] = o1;
        float s = v0.x + v0.y + v0.z + v0.w + v1.x + v1.y + v1.z + v1.w
                + v2.x + v2.y + v2.z + v2.w + v3.x + v3.y + v3.z + v3.w;
        z_s[r][f] = s * (1.0f / 16.0f);
    }
    __syncthreads();
    if (tid < 64) {
        int b = b0 + tid;
        float s1[13];
        #pragma unroll
        for (int o = 0; o < 13; ++o) {
            float acc = 0.f;
            #pragma unroll
            for (int f = 0; f < F_FIELDS; ++f) acc = fmaf(z_s[tid][f], sw1_s[f * 13 + o], acc);
            s1[o] = fmaxf(acc, 0.0f);
        }
        #pragma unroll
        for (int f = 0; f < F_FIELDS; ++f) {
            float acc = 0.f;
            #pragma unroll
            for (int o = 0; o < 13; ++o) acc = fmaf(s1[o], sw2_s[o * F_FIELDS + f], acc);
            aG[(size_t)b * F_FIELDS + f] = fmaxf(acc, 0.0f);
        }
    }
}

// ---------------- K2: chained-MFMA bilinear + big GEMM ----------------
// grid 256 blocks x 1024 thr (16 waves = 4/SIMD). Block owns 64 batch rows;
// wave w owns pair chunk w. Per pair: 4x t-MFMA (pipelined 1 ahead) +
// perm-packed A-build + 16 y-MFMA. Weights prefetched 1 pair ahead.
// No barriers in the pair loop.
__global__ __launch_bounds__(1024, 4) void k_main(
        const unsigned short* __restrict__ eG, const float* __restrict__ aG,
        const unsigned short* __restrict__ w1cat, const unsigned short* __restrict__ wcat,
        unsigned short* __restrict__ ypart) {
    __shared__ __align__(16) unsigned short eS[64 * 424];
    __shared__ float aS[F_FIELDS * 64];
    const int tid = threadIdx.x;
    const int b0 = blockIdx.x * 64;

    for (int i = tid; i < 64 * 52; i += 1024) {
        int r = i / 52, seg = i - r * 52;
        int4 v = ((const int4*)(eG + (size_t)(b0 + r) * 416))[seg];
        *(int4*)(eS + r * 424 + seg * 8) = v;
    }
    for (int i = tid; i < F_FIELDS * 64; i += 1024) {
        int f = i >> 6, b = i & 63;
        aS[f * 64 + b] = aG[(size_t)(b0 + b) * F_FIELDS + f];
    }
    __syncthreads();

    const int w    = tid >> 6;      // wave = chunk id, 0..15
    const int lane = tid & 63;
    const int ln   = lane & 15;
    const int q    = lane >> 4;
    const int p0 = CHUNK[w], p1 = CHUNK[w + 1];

    f32x4 acc[4][4];
    #pragma unroll
    for (int a = 0; a < 4; ++a)
        #pragma unroll
        for (int b = 0; b < 4; ++b) acc[a][b] = (f32x4){0.f, 0.f, 0.f, 0.f};
    const f32x4 zero4 = {0.f, 0.f, 0.f, 0.f};

    // prologue: weights + e_i frags + t for p0
    int iu_c = PT.iu[p0];
    bf16x8 eiB[4];
    float ai[4];
    #pragma unroll
    for (int mt = 0; mt < 4; ++mt) {
        eiB[mt] = __builtin_bit_cast(bf16x8,
            *(const int4*)(eS + (mt * 16 + ln) * 424 + iu_c * 16 + (q & 1) * 8));
        ai[mt] = aS[iu_c * 64 + mt * 16 + ln];
    }
    bf16x8 wa_c = __builtin_bit_cast(bf16x8, *(const int4*)(wcat + (size_t)p0 * 512 + ln * 32 + q * 8));
    bf16x8 wb_c[4];
    #pragma unroll
    for (int nt = 0; nt < 4; ++nt)
        wb_c[nt] = __builtin_bit_cast(bf16x8, *(const int4*)(w1cat + (size_t)p0 * 2048 + (nt * 16 + ln) * 32 + q * 8));
    f32x4 tc[4];
    #pragma unroll
    for (int mt = 0; mt < 4; ++mt)
        tc[mt] = __builtin_amdgcn_mfma_f32_16x16x32_bf16(wa_c, eiB[mt], zero4, 0, 0, 0);

    for (int p = p0; p < p1; ++p) {
        const bool more = (p + 1 < p1);
        bf16x8 wa_n, wb_n[4];
        if (more) {
            wa_n = __builtin_bit_cast(bf16x8, *(const int4*)(wcat + (size_t)(p + 1) * 512 + ln * 32 + q * 8));
            #pragma unroll
            for (int nt = 0; nt < 4; ++nt)
                wb_n[nt] = __builtin_bit_cast(bf16x8, *(const int4*)(w1cat + (size_t)(p + 1) * 2048 + (nt * 16 + ln) * 32 + q * 8));
        }
        const int ju = PT.ju[p];
        uint2 ejv[4];
        float cv[4];
        #pragma unroll
        for (int mt = 0; mt < 4; ++mt) {
            ejv[mt] = *(const uint2*)(eS + (mt * 16 + ln) * 424 + ju * 16 + q * 4);
            cv[mt]  = ai[mt] * aS[ju * 64 + mt * 16 + ln];
        }
        // issue t for p+1 before consuming tc (software pipeline)
        f32x4 tn[4];
        if (more) {
            const int iu_n = PT.iu[p + 1];
            if (iu_n != iu_c) {
                iu_c = iu_n;
                #pragma unroll
                for (int mt = 0; mt < 4; ++mt) {
                    eiB[mt] = __builtin_bit_cast(bf16x8,
                        *(const int4*)(eS + (mt * 16 + ln) * 424 + iu_c * 16 + (q & 1) * 8));
                    ai[mt] = aS[iu_c * 64 + mt * 16 + ln];
                }
            }
            #pragma unroll
            for (int mt = 0; mt < 4; ++mt)
                tn[mt] = __builtin_amdgcn_mfma_f32_16x16x32_bf16(wa_n, eiB[mt], zero4, 0, 0, 0);
        }
        #pragma unroll
        for (int mt = 0; mt < 4; ++mt) {
            float e0 = bflo(ejv[mt].x), e1 = bfhi(ejv[mt].x);
            float e2 = bflo(ejv[mt].y), e3 = bfhi(ejv[mt].y);
            float c  = cv[mt];
            float u0 = tc[mt][0] * e0, u1 = tc[mt][1] * e1;
            float u2 = tc[mt][2] * e2, u3 = tc[mt][3] * e3;
            int4 af;
            af.x = (int)pk_trunc(u0, c * u0);
            af.y = (int)pk_trunc(u1, c * u1);
            af.z = (int)pk_trunc(u2, c * u2);
            af.w = (int)pk_trunc(u3, c * u3);
            bf16x8 A = __builtin_bit_cast(bf16x8, af);
            #pragma unroll
            for (int nt = 0; nt < 4; ++nt)
                acc[mt][nt] = __builtin_amdgcn_mfma_f32_16x16x32_bf16(A, wb_c[nt], acc[mt][nt], 0, 0, 0);
        }
        if (more) {
            #pragma unroll
            for (int mt = 0; mt < 4; ++mt) tc[mt] = tn[mt];
            wa_c = wa_n;
            #pragma unroll
            for (int nt = 0; nt < 4; ++nt) wb_c[nt] = wb_n[nt];
        }
    }

    unsigned short* yp = ypart + ((size_t)w * BATCH + b0) * 64;
    #pragma unroll
    for (int mt = 0; mt < 4; ++mt)
        #pragma unroll
        for (int nt = 0; nt < 4; ++nt)
            #pragma unroll
            for (int r = 0; r < 4; ++r)
                yp[(mt * 16 + q * 4 + r) * 64 + nt * 16 + ln] = bf16u(acc[mt][nt][r]);
}

// ---------------- K3: merge 16 bf16 partials + BN/ReLU MLP tail ----------------
__global__ __launch_bounds__(256) void k_epi(
        const unsigned short* __restrict__ ypart,
        const float* __restrict__ b1, const float* __restrict__ g1,
        const float* __restrict__ be1, const float* __restrict__ m1,
        const float* __restrict__ v1,
        const float* __restrict__ w2, const float* __restrict__ b2,
        const float* __restrict__ g2, const float* __restrict__ be2,
        const float* __restrict__ m2, const float* __restrict__ v2,
        const float* __restrict__ w3, const float* __restrict__ b3,
        float* __restrict__ out) {
    __shared__ __align__(16) float h1s[64 * 64];
    __shared__ float h2s[64 * 36];
    const int tid = threadIdx.x;
    const int b0 = blockIdx.x * 64;
    const int rr = tid >> 2;
    const int cc = (tid & 3) << 4;

    float s[16];
    #pragma unroll
    for (int i = 0; i < 16; ++i) s[i] = 0.f;
    for (int part = 0; part < 16; ++part) {
        const unsigned short* src = ypart + ((size_t)part * BATCH + b0 + rr) * 64 + cc;
        int4 A = ((const int4*)src)[0];
        int4 Bv = ((const int4*)src)[1];
        s[0] += bflo(A.x);  s[1] += bfhi(A.x);  s[2] += bflo(A.y);  s[3] += bfhi(A.y);
        s[4] += bflo(A.z);  s[5] += bfhi(A.z);  s[6] += bflo(A.w);  s[7] += bfhi(A.w);
        s[8] += bflo(Bv.x); s[9] += bfhi(Bv.x); s[10] += bflo(Bv.y); s[11] += bfhi(Bv.y);
        s[12] += bflo(Bv.z); s[13] += bfhi(Bv.z); s[14] += bflo(Bv.w); s[15] += bfhi(Bv.w);
    }
    #pragma unroll
    for (int g = 0; g < 4; ++g) {
        int o = cc + g * 4;
        float4 gg = *(const float4*)(g1 + o);
        float4 vv = *(const float4*)(v1 + o);
        float4 mm = *(const float4*)(m1 + o);
        float4 bb = *(const float4*)(be1 + o);
        float4 bi = *(const float4*)(b1 + o);
        float4 h;
        h.x = fmaxf(gg.x * (s[g*4+0] + bi.x - mm.x) * rsqrtf(vv.x + BN_EPS) + bb.x, 0.f);
        h.y = fmaxf(gg.y * (s[g*4+1] + bi.y - mm.y) * rsqrtf(vv.y + BN_EPS) + bb.y, 0.f);
        h.z = fmaxf(gg.z * (s[g*4+2] + bi.z - mm.z) * rsqrtf(vv.z + BN_EPS) + bb.z, 0.f);
        h.w = fmaxf(gg.w * (s[g*4+3] + bi.w - mm.w) * rsqrtf(vv.w + BN_EPS) + bb.w, 0.f);
        *(float4*)(h1s + rr * 64 + o) = h;
    }
    __syncthreads();

    const int r2 = tid >> 2;
    const int og2 = (tid & 3) << 3;
    float a2[8];
    #pragma unroll
    for (int qq = 0; qq < 8; ++qq) a2[qq] = 0.f;
    #pragma unroll 8
    for (int k = 0; k < 64; ++k) {
        float hk = h1s[r2 * 64 + k];
        float4 wa = *(const float4*)(w2 + k * 32 + og2);
        float4 wb = *(const float4*)(w2 + k * 32 + og2 + 4);
        a2[0] = fmaf(hk, wa.x, a2[0]); a2[1] = fmaf(hk, wa.y, a2[1]);
        a2[2] = fmaf(hk, wa.z, a2[2]); a2[3] = fmaf(hk, wa.w, a2[3]);
        a2[4] = fmaf(hk, wb.x, a2[4]); a2[5] = fmaf(hk, wb.y, a2[5]);
        a2[6] = fmaf(hk, wb.z, a2[6]); a2[7] = fmaf(hk, wb.w, a2[7]);
    }
    #pragma unroll
    for (int qq = 0; qq < 8; ++qq) {
        int o = og2 + qq;
        float val = g2[o] * (a2[qq] + b2[o] - m2[o]) * rsqrtf(v2[o] + BN_EPS) + be2[o];
        h2s[r2 * 36 + o] = fmaxf(val, 0.f);
    }
    __syncthreads();
    if (tid < 64) {
        float sacc = b3[0];
        #pragma unroll
        for (int k = 0; k < 32; ++k) sacc = fmaf(h2s[tid * 36 + k], w3[k], sacc);
        out[b0 + tid] = 1.0f / (1.0f + expf(-sacc));
    }
}

extern "C" void kernel_launch(void* const* d_in, const int* in_sizes, int n_in,
                              void* d_out, int out_size, void* d_ws, size_t ws_size,
                              hipStream_t stream) {
    const int*   x   = (const int*)d_in[0];
    const float* emb = (const float*)d_in[1];
    const float* sw1 = (const float*)d_in[2];
    const float* sw2 = (const float*)d_in[3];
    const float* blw = (const float*)d_in[4];
    const float* w1  = (const float*)d_in[5];
    const float* b1  = (const float*)d_in[6];
    const float* g1  = (const float*)d_in[7];
    const float* be1 = (const float*)d_in[8];
    const float* m1  = (const float*)d_in[9];
    const float* v1  = (const float*)d_in[10];
    const float* w2  = (const float*)d_in[11];
    const float* b2  = (const float*)d_in[12];
    const float* g2  = (const float*)d_in[13];
    const float* be2 = (const float*)d_in[14];
    const float* m2  = (const float*)d_in[15];
    const float* v2  = (const float*)d_in[16];
    const float* w3  = (const float*)d_in[17];
    const float* b3  = (const float*)d_in[18];
    float* out = (float*)d_out;

    // ws layout (bytes): eG 13,631,488 | aG 1,703,936 | w1cat 1,331,200 |
    // wcat 332,800 | ypart 33,554,432  -> ~50.6 MB
    char* ws = (char*)d_ws;
    unsigned short* eG    = (unsigned short*)ws;
    float*          aG    = (float*)(ws + 13631488);
    unsigned short* w1cat = (unsigned short*)(ws + 15335424);
    unsigned short* wcat  = (unsigned short*)(ws + 16666624);
    unsigned short* ypart = (unsigned short*)(ws + 16999424);

    hipLaunchKernelGGL(k_prep, dim3(581), dim3(256), 0, stream,
                       x, emb, sw1, sw2, w1, blw, eG, aG, w1cat, wcat);
    hipLaunchKernelGGL(k_main, dim3(256), dim3(1024), 0, stream, eG, aG, w1cat, wcat, ypart);
    hipLaunchKernelGGL(k_epi,  dim3(256), dim3(256), 0, stream, ypart,
                       b1, g1, be1, m1, v1, w2, b2, g2, be2, m2, v2, w3, b3, out);
}

// Round 8
// 171.046 us; speedup vs baseline: 2.5981x; 2.5981x over previous
//
#include <hip/hip_runtime.h>
#include <cstdint>
#include <cstddef>

// FiBiNET fused inference — MFMA bf16, chained-layout, fused gather+GEMM.
// R8: 32-row blocks (acc 32 AGPR -> ~122 total regs, 4 waves/SIMD honest),
// grid 512x512thr, gather+SE fused into k_main (no eG round-trip),
// pairs padded to 336 = 8 uniform chunks of 42 (dummy pairs zero-weighted).
// Chain: t^T = W_p^T @ e_i^T (16x16x32, K-pad in wcat) lands lanes at the
// y-MFMA A-operand slot (m=lane&15=batch, k'=2d+{u,cu}=q*8+j).
// eS in USHORT units: field f at f*16 (32 B). Row stride 424 ush.

#define F_FIELDS 26
#define P_PAIRS 325
#define PAD_PAIRS 336
#define BATCH 16384
#define BN_EPS 1e-3f

typedef short bf16x8 __attribute__((ext_vector_type(8)));
typedef float f32x4 __attribute__((ext_vector_type(4)));

struct PairTab { unsigned char iu[PAD_PAIRS]; unsigned char ju[PAD_PAIRS]; };
static constexpr PairTab make_pairs() {
    PairTab t{};
    int p = 0;
    for (int a = 0; a < F_FIELDS; ++a)
        for (int b = a + 1; b < F_FIELDS; ++b) { t.iu[p] = (unsigned char)a; t.ju[p] = (unsigned char)b; ++p; }
    for (; p < PAD_PAIRS; ++p) { t.iu[p] = 0; t.ju[p] = 0; }
    return t;
}
__constant__ PairTab PT = make_pairs();

__device__ __forceinline__ unsigned short bf16u(float v) {
    unsigned u = __float_as_uint(v);
    unsigned r = (u + 0x7fffu + ((u >> 16) & 1u)) >> 16;
    return (unsigned short)r;
}
__device__ __forceinline__ unsigned pk_bf16(float lo, float hi) {
    return (unsigned)bf16u(lo) | ((unsigned)bf16u(hi) << 16);
}
__device__ __forceinline__ float bflo(unsigned d) { return __uint_as_float(d << 16); }
__device__ __forceinline__ float bfhi(unsigned d) { return __uint_as_float(d & 0xffff0000u); }
__device__ __forceinline__ unsigned pk_trunc(float u, float cu) {
    return __builtin_amdgcn_perm(__float_as_uint(cu), __float_as_uint(u), 0x07060302u);
}

// ---------------- K0: weight repack (coalesced, LDS transpose) ----------------
// w1cat [336][64 o][32 k'], k'=2d+su: su=0 -> w1[p*16+d][o], su=1 -> w1[5200+p*16+d][o]
// wcat  [336][16 dout][32 din] = W_p^T, din 16..31 zeroed. p>=325 all-zero.
__global__ __launch_bounds__(256) void k_wprep(const float* __restrict__ w1,
        const float* __restrict__ blw, unsigned short* __restrict__ w1cat,
        unsigned short* __restrict__ wcat) {
    const int p = blockIdx.x;
    const int tid = threadIdx.x;
    if (p >= P_PAIRS) {
        int4 z = make_int4(0, 0, 0, 0);
        *(int4*)(w1cat + (size_t)p * 2048 + tid * 8) = z;
        if (tid < 64) *(int4*)(wcat + (size_t)p * 512 + tid * 8) = z;
        return;
    }
    __shared__ float wu[1024], wv[1024], wb[256];
    ((float4*)wu)[tid] = ((const float4*)(w1 + (size_t)p * 1024))[tid];
    ((float4*)wv)[tid] = ((const float4*)(w1 + 332800 + (size_t)p * 1024))[tid];
    if (tid < 64) ((float4*)wb)[tid] = ((const float4*)(blw + (size_t)p * 256))[tid];
    __syncthreads();
    {
        int base = tid * 8;
        int o = base >> 5, k0 = base & 31;
        unsigned short outv[8];
        #pragma unroll
        for (int j = 0; j < 8; ++j) {
            int k = k0 + j, d = k >> 1, su = k & 1;
            outv[j] = bf16u(su ? wv[d * 64 + o] : wu[d * 64 + o]);
        }
        *(int4*)(w1cat + (size_t)p * 2048 + base) = *(const int4*)outv;
    }
    if (tid < 64) {
        int base = tid * 8;
        int dout = base >> 5, din0 = base & 31;
        unsigned short outv[8];
        #pragma unroll
        for (int j = 0; j < 8; ++j) {
            int din = din0 + j;
            outv[j] = (din < 16) ? bf16u(wb[din * 16 + dout]) : (unsigned short)0;
        }
        *(int4*)(wcat + (size_t)p * 512 + base) = *(const int4*)outv;
    }
}

// ---------------- K1: fused gather + SE + chained-MFMA GEMM ----------------
// grid 512 blocks x 512 thr (8 waves). Block owns 32 batch rows (2 m-tiles);
// wave w owns pair chunk [42w, 42w+42). LDS ~36.5 KB -> 2 blocks/CU ->
// 16 waves/CU = 4/SIMD (total regs must be <=128: acc 32 AGPR + ~90 VGPR).
__global__ __launch_bounds__(512, 4) void k_main(const int* __restrict__ x,
        const float* __restrict__ emb, const float* __restrict__ sw1,
        const float* __restrict__ sw2, const unsigned short* __restrict__ w1cat,
        const unsigned short* __restrict__ wcat, unsigned short* __restrict__ ypart) {
    __shared__ __align__(16) unsigned short eS[32 * 424];
    __shared__ float aS[F_FIELDS * 32];
    __shared__ float z_s[32][F_FIELDS];
    __shared__ float sw1_s[F_FIELDS * 13];
    __shared__ float sw2_s[13 * F_FIELDS];
    const int tid = threadIdx.x;
    const int b0 = blockIdx.x * 32;

    for (int i = tid; i < F_FIELDS * 13; i += 512) { sw1_s[i] = sw1[i]; sw2_s[i] = sw2[i]; }
    for (int idx = tid; idx < 32 * F_FIELDS; idx += 512) {
        int r = idx / F_FIELDS, f = idx - r * F_FIELDS;
        int id = x[(b0 + r) * F_FIELDS + f] + f * 1000;
        const float4* src = (const float4*)(emb + (size_t)id * 16);
        float4 v0 = src[0], v1 = src[1], v2 = src[2], v3 = src[3];
        int4 o0, o1;
        o0.x = (int)pk_bf16(v0.x, v0.y); o0.y = (int)pk_bf16(v0.z, v0.w);
        o0.z = (int)pk_bf16(v1.x, v1.y); o0.w = (int)pk_bf16(v1.z, v1.w);
        o1.x = (int)pk_bf16(v2.x, v2.y); o1.y = (int)pk_bf16(v2.z, v2.w);
        o1.z = (int)pk_bf16(v3.x, v3.y); o1.w = (int)pk_bf16(v3.z, v3.w);
        *(int4*)(eS + r * 424 + f * 16) = o0;
        *(int4*)(eS + r * 424 + f * 16 + 8) = o1;
        float s = v0.x + v0.y + v0.z + v0.w + v1.x + v1.y + v1.z + v1.w
                + v2.x + v2.y + v2.z + v2.w + v3.x + v3.y + v3.z + v3.w;
        z_s[r][f] = s * (1.0f / 16.0f);
    }
    __syncthreads();
    if (tid < 32) {
        float s1[13];
        #pragma unroll
        for (int o = 0; o < 13; ++o) {
            float acc0 = 0.f;
            #pragma unroll
            for (int f = 0; f < F_FIELDS; ++f) acc0 = fmaf(z_s[tid][f], sw1_s[f * 13 + o], acc0);
            s1[o] = fmaxf(acc0, 0.0f);
        }
        #pragma unroll
        for (int f = 0; f < F_FIELDS; ++f) {
            float acc0 = 0.f;
            #pragma unroll
            for (int o = 0; o < 13; ++o) acc0 = fmaf(s1[o], sw2_s[o * F_FIELDS + f], acc0);
            aS[f * 32 + tid] = fmaxf(acc0, 0.0f);
        }
    }
    __syncthreads();

    const int w    = tid >> 6;
    const int lane = tid & 63;
    const int ln   = lane & 15;
    const int q    = lane >> 4;
    const int p0 = w * 42, p1 = p0 + 42;

    f32x4 acc[2][4];
    #pragma unroll
    for (int a = 0; a < 2; ++a)
        #pragma unroll
        for (int b = 0; b < 4; ++b) acc[a][b] = (f32x4){0.f, 0.f, 0.f, 0.f};
    const f32x4 zero4 = {0.f, 0.f, 0.f, 0.f};

    int iu_c = PT.iu[p0];
    bf16x8 eiB[2];
    float ai[2];
    #pragma unroll
    for (int mt = 0; mt < 2; ++mt) {
        eiB[mt] = __builtin_bit_cast(bf16x8,
            *(const int4*)(eS + (mt * 16 + ln) * 424 + iu_c * 16 + (q & 1) * 8));
        ai[mt] = aS[iu_c * 32 + mt * 16 + ln];
    }
    bf16x8 wa_c = __builtin_bit_cast(bf16x8, *(const int4*)(wcat + (size_t)p0 * 512 + ln * 32 + q * 8));
    bf16x8 wb_c[4];
    #pragma unroll
    for (int nt = 0; nt < 4; ++nt)
        wb_c[nt] = __builtin_bit_cast(bf16x8, *(const int4*)(w1cat + (size_t)p0 * 2048 + (nt * 16 + ln) * 32 + q * 8));

    #pragma unroll 2
    for (int p = p0; p < p1; ++p) {
        const int pn = (p + 1 < p1) ? (p + 1) : p;
        bf16x8 wa_n = __builtin_bit_cast(bf16x8, *(const int4*)(wcat + (size_t)pn * 512 + ln * 32 + q * 8));
        bf16x8 wb_n[4];
        #pragma unroll
        for (int nt = 0; nt < 4; ++nt)
            wb_n[nt] = __builtin_bit_cast(bf16x8, *(const int4*)(w1cat + (size_t)pn * 2048 + (nt * 16 + ln) * 32 + q * 8));

        const int ju = PT.ju[p];
        uint2 ejv[2];
        float cv[2];
        #pragma unroll
        for (int mt = 0; mt < 2; ++mt) {
            ejv[mt] = *(const uint2*)(eS + (mt * 16 + ln) * 424 + ju * 16 + q * 4);
            cv[mt]  = ai[mt] * aS[ju * 32 + mt * 16 + ln];
        }
        #pragma unroll
        for (int mt = 0; mt < 2; ++mt) {
            f32x4 t = __builtin_amdgcn_mfma_f32_16x16x32_bf16(wa_c, eiB[mt], zero4, 0, 0, 0);
            float e0 = bflo(ejv[mt].x), e1 = bfhi(ejv[mt].x);
            float e2 = bflo(ejv[mt].y), e3 = bfhi(ejv[mt].y);
            float c  = cv[mt];
            float u0 = t[0] * e0, u1 = t[1] * e1, u2 = t[2] * e2, u3 = t[3] * e3;
            int4 af;
            af.x = (int)pk_trunc(u0, c * u0);
            af.y = (int)pk_trunc(u1, c * u1);
            af.z = (int)pk_trunc(u2, c * u2);
            af.w = (int)pk_trunc(u3, c * u3);
            bf16x8 A = __builtin_bit_cast(bf16x8, af);
            #pragma unroll
            for (int nt = 0; nt < 4; ++nt)
                acc[mt][nt] = __builtin_amdgcn_mfma_f32_16x16x32_bf16(A, wb_c[nt], acc[mt][nt], 0, 0, 0);
        }
        const int iu_n = PT.iu[pn];
        if (iu_n != iu_c) {
            iu_c = iu_n;
            #pragma unroll
            for (int mt = 0; mt < 2; ++mt) {
                eiB[mt] = __builtin_bit_cast(bf16x8,
                    *(const int4*)(eS + (mt * 16 + ln) * 424 + iu_c * 16 + (q & 1) * 8));
                ai[mt] = aS[iu_c * 32 + mt * 16 + ln];
            }
        }
        wa_c = wa_n;
        #pragma unroll
        for (int nt = 0; nt < 4; ++nt) wb_c[nt] = wb_n[nt];
    }

    unsigned short* yp = ypart + ((size_t)w * BATCH + b0) * 64;
    #pragma unroll
    for (int mt = 0; mt < 2; ++mt)
        #pragma unroll
        for (int nt = 0; nt < 4; ++nt)
            #pragma unroll
            for (int r = 0; r < 4; ++r)
                yp[(mt * 16 + q * 4 + r) * 64 + nt * 16 + ln] = bf16u(acc[mt][nt][r]);
}

// ---------------- K2: merge 8 bf16 partials + BN/ReLU MLP tail ----------------
__global__ __launch_bounds__(256) void k_epi(
        const unsigned short* __restrict__ ypart,
        const float* __restrict__ b1, const float* __restrict__ g1,
        const float* __restrict__ be1, const float* __restrict__ m1,
        const float* __restrict__ v1,
        const float* __restrict__ w2, const float* __restrict__ b2,
        const float* __restrict__ g2, const float* __restrict__ be2,
        const float* __restrict__ m2, const float* __restrict__ v2,
        const float* __restrict__ w3, const float* __restrict__ b3,
        float* __restrict__ out) {
    __shared__ __align__(16) float h1s[64 * 64];
    __shared__ float h2s[64 * 36];
    const int tid = threadIdx.x;
    const int b0 = blockIdx.x * 64;
    const int rr = tid >> 2;
    const int cc = (tid & 3) << 4;

    float s[16];
    #pragma unroll
    for (int i = 0; i < 16; ++i) s[i] = 0.f;
    for (int part = 0; part < 8; ++part) {
        const unsigned short* src = ypart + ((size_t)part * BATCH + b0 + rr) * 64 + cc;
        int4 A = ((const int4*)src)[0];
        int4 Bv = ((const int4*)src)[1];
        s[0] += bflo(A.x);  s[1] += bfhi(A.x);  s[2] += bflo(A.y);  s[3] += bfhi(A.y);
        s[4] += bflo(A.z);  s[5] += bfhi(A.z);  s[6] += bflo(A.w);  s[7] += bfhi(A.w);
        s[8] += bflo(Bv.x); s[9] += bfhi(Bv.x); s[10] += bflo(Bv.y); s[11] += bfhi(Bv.y);
        s[12] += bflo(Bv.z); s[13] += bfhi(Bv.z); s[14] += bflo(Bv.w); s[15] += bfhi(Bv.w);
    }
    #pragma unroll
    for (int g = 0; g < 4; ++g) {
        int o = cc + g * 4;
        float4 gg = *(const float4*)(g1 + o);
        float4 vv = *(const float4*)(v1 + o);
        float4 mm = *(const float4*)(m1 + o);
        float4 bb = *(const float4*)(be1 + o);
        float4 bi = *(const float4*)(b1 + o);
        float4 h;
        h.x = fmaxf(gg.x * (s[g*4+0] + bi.x - mm.x) * rsqrtf(vv.x + BN_EPS) + bb.x, 0.f);
        h.y = fmaxf(gg.y * (s[g*4+1] + bi.y - mm.y) * rsqrtf(vv.y + BN_EPS) + bb.y, 0.f);
        h.z = fmaxf(gg.z * (s[g*4+2] + bi.z - mm.z) * rsqrtf(vv.z + BN_EPS) + bb.z, 0.f);
        h.w = fmaxf(gg.w * (s[g*4+3] + bi.w - mm.w) * rsqrtf(vv.w + BN_EPS) + bb.w, 0.f);
        *(float4*)(h1s + rr * 64 + o) = h;
    }
    __syncthreads();

    const int r2 = tid >> 2;
    const int og2 = (tid & 3) << 3;
    float a2[8];
    #pragma unroll
    for (int qq = 0; qq < 8; ++qq) a2[qq] = 0.f;
    #pragma unroll 8
    for (int k = 0; k < 64; ++k) {
        float hk = h1s[r2 * 64 + k];
        float4 wa = *(const float4*)(w2 + k * 32 + og2);
        float4 wb = *(const float4*)(w2 + k * 32 + og2 + 4);
        a2[0] = fmaf(hk, wa.x, a2[0]); a2[1] = fmaf(hk, wa.y, a2[1]);
        a2[2] = fmaf(hk, wa.z, a2[2]); a2[3] = fmaf(hk, wa.w, a2[3]);
        a2[4] = fmaf(hk, wb.x, a2[4]); a2[5] = fmaf(hk, wb.y, a2[5]);
        a2[6] = fmaf(hk, wb.z, a2[6]); a2[7] = fmaf(hk, wb.w, a2[7]);
    }
    #pragma unroll
    for (int qq = 0; qq < 8; ++qq) {
        int o = og2 + qq;
        float val = g2[o] * (a2[qq] + b2[o] - m2[o]) * rsqrtf(v2[o] + BN_EPS) + be2[o];
        h2s[r2 * 36 + o] = fmaxf(val, 0.f);
    }
    __syncthreads();
    if (tid < 64) {
        float sacc = b3[0];
        #pragma unroll
        for (int k = 0; k < 32; ++k) sacc = fmaf(h2s[tid * 36 + k], w3[k], sacc);
        out[b0 + tid] = 1.0f / (1.0f + expf(-sacc));
    }
}

extern "C" void kernel_launch(void* const* d_in, const int* in_sizes, int n_in,
                              void* d_out, int out_size, void* d_ws, size_t ws_size,
                              hipStream_t stream) {
    const int*   x   = (const int*)d_in[0];
    const float* emb = (const float*)d_in[1];
    const float* sw1 = (const float*)d_in[2];
    const float* sw2 = (const float*)d_in[3];
    const float* blw = (const float*)d_in[4];
    const float* w1  = (const float*)d_in[5];
    const float* b1  = (const float*)d_in[6];
    const float* g1  = (const float*)d_in[7];
    const float* be1 = (const float*)d_in[8];
    const float* m1  = (const float*)d_in[9];
    const float* v1  = (const float*)d_in[10];
    const float* w2  = (const float*)d_in[11];
    const float* b2  = (const float*)d_in[12];
    const float* g2  = (const float*)d_in[13];
    const float* be2 = (const float*)d_in[14];
    const float* m2  = (const float*)d_in[15];
    const float* v2  = (const float*)d_in[16];
    const float* w3  = (const float*)d_in[17];
    const float* b3  = (const float*)d_in[18];
    float* out = (float*)d_out;

    // ws (bytes): w1cat 1,376,256 | wcat 344,064 | ypart 16,777,216 -> ~18.5 MB
    char* ws = (char*)d_ws;
    unsigned short* w1cat = (unsigned short*)ws;
    unsigned short* wcat  = (unsigned short*)(ws + 1376256);
    unsigned short* ypart = (unsigned short*)(ws + 1720320);

    hipLaunchKernelGGL(k_wprep, dim3(PAD_PAIRS), dim3(256), 0, stream, w1, blw, w1cat, wcat);
    hipLaunchKernelGGL(k_main,  dim3(512), dim3(512), 0, stream,
                       x, emb, sw1, sw2, w1cat, wcat, ypart);
    hipLaunchKernelGGL(k_epi,   dim3(256), dim3(256), 0, stream, ypart,
                       b1, g1, be1, m1, v1, w2, b2, g2, be2, m2, v2, w3, b3, out);
}

// Round 9
// 150.541 us; speedup vs baseline: 2.9519x; 1.1362x over previous
//
#include <hip/hip_runtime.h>
#include <cstdint>
#include <cstddef>

// FiBiNET fused inference — MFMA bf16, chained-layout, fused gather+GEMM.
// R9: all hot global accesses lane-contiguous:
//   wcatL [336][64 lane][8]   (= W_p^T frag, K-pad baked)
//   w1catL[336][4 nt][64 lane][8]
//   ybuf  [8 w][512 mg][4 s][64 lane][4 uint]  (bf16-pair packed C-frags)
// Chain: t^T = W_p^T @ e_i^T (16x16x32) lands lanes at the y-MFMA A-slot
// (m=lane&15=batch, k'=2d+{u,cu}=q*8+j). No barriers in the pair loop.
// eS in USHORT units: field f at f*16 (32 B). Row stride 424 ush.

#define F_FIELDS 26
#define P_PAIRS 325
#define PAD_PAIRS 336
#define BATCH 16384
#define BN_EPS 1e-3f

typedef short bf16x8 __attribute__((ext_vector_type(8)));
typedef float f32x4 __attribute__((ext_vector_type(4)));

struct PairTab { unsigned char iu[PAD_PAIRS]; unsigned char ju[PAD_PAIRS]; };
static constexpr PairTab make_pairs() {
    PairTab t{};
    int p = 0;
    for (int a = 0; a < F_FIELDS; ++a)
        for (int b = a + 1; b < F_FIELDS; ++b) { t.iu[p] = (unsigned char)a; t.ju[p] = (unsigned char)b; ++p; }
    for (; p < PAD_PAIRS; ++p) { t.iu[p] = 0; t.ju[p] = 0; }
    return t;
}
__constant__ PairTab PT = make_pairs();

__device__ __forceinline__ unsigned short bf16u(float v) {
    unsigned u = __float_as_uint(v);
    unsigned r = (u + 0x7fffu + ((u >> 16) & 1u)) >> 16;
    return (unsigned short)r;
}
__device__ __forceinline__ unsigned pk_bf16(float lo, float hi) {
    return (unsigned)bf16u(lo) | ((unsigned)bf16u(hi) << 16);
}
__device__ __forceinline__ float bflo(unsigned d) { return __uint_as_float(d << 16); }
__device__ __forceinline__ float bfhi(unsigned d) { return __uint_as_float(d & 0xffff0000u); }
__device__ __forceinline__ unsigned pk_trunc(float u, float cu) {
    return __builtin_amdgcn_perm(__float_as_uint(cu), __float_as_uint(u), 0x07060302u);
}

// ---------------- K0: weight repack into lane-contiguous frag layouts ----------
__global__ __launch_bounds__(256) void k_wprep(const float* __restrict__ w1,
        const float* __restrict__ blw, unsigned short* __restrict__ w1catL,
        unsigned short* __restrict__ wcatL) {
    const int p = blockIdx.x;
    const int tid = threadIdx.x;
    if (p >= P_PAIRS) {
        int4 z = make_int4(0, 0, 0, 0);
        *(int4*)(w1catL + (size_t)p * 2048 + tid * 8) = z;
        if (tid < 64) *(int4*)(wcatL + (size_t)p * 512 + tid * 8) = z;
        return;
    }
    __shared__ float wu[1024], wv[1024], wb[256];
    ((float4*)wu)[tid] = ((const float4*)(w1 + (size_t)p * 1024))[tid];
    ((float4*)wv)[tid] = ((const float4*)(w1 + 332800 + (size_t)p * 1024))[tid];
    if (tid < 64) ((float4*)wb)[tid] = ((const float4*)(blw + (size_t)p * 256))[tid];
    __syncthreads();
    {   // w1catL[p][nt][lane][8]: element [o=nt*16+ln][k'=q*8+j], k'=2d+su
        int nt = tid >> 6, lane = tid & 63, ln = lane & 15, q = lane >> 4;
        int o = nt * 16 + ln;
        unsigned short outv[8];
        #pragma unroll
        for (int j = 0; j < 8; ++j) {
            int k = q * 8 + j, d = k >> 1, su = k & 1;
            outv[j] = bf16u(su ? wv[d * 64 + o] : wu[d * 64 + o]);
        }
        *(int4*)(w1catL + (size_t)p * 2048 + tid * 8) = *(const int4*)outv;
    }
    if (tid < 64) {  // wcatL[p][lane][8]: element [dout=ln][din=q*8+j], pad din>=16
        int ln = tid & 15, q = tid >> 4;
        unsigned short outv[8];
        #pragma unroll
        for (int j = 0; j < 8; ++j) {
            int din = q * 8 + j;
            outv[j] = (din < 16) ? bf16u(wb[din * 16 + ln]) : (unsigned short)0;
        }
        *(int4*)(wcatL + (size_t)p * 512 + tid * 8) = *(const int4*)outv;
    }
}

// ---------------- K1: fused gather + SE + chained-MFMA GEMM ----------------
// grid 512 blocks x 512 thr (8 waves). Block owns 32 batch rows (2 m-tiles);
// wave w owns pairs [42w, 42w+42). All frag loads/stores lane-contiguous.
__global__ __launch_bounds__(512, 4) void k_main(const int* __restrict__ x,
        const float* __restrict__ emb, const float* __restrict__ sw1,
        const float* __restrict__ sw2, const unsigned short* __restrict__ w1catL,
        const unsigned short* __restrict__ wcatL, unsigned* __restrict__ ybuf) {
    __shared__ __align__(16) unsigned short eS[32 * 424];
    __shared__ float aS[F_FIELDS * 32];
    __shared__ float z_s[32][F_FIELDS];
    __shared__ float sw1_s[F_FIELDS * 13];
    __shared__ float sw2_s[13 * F_FIELDS];
    const int tid = threadIdx.x;
    const int b0 = blockIdx.x * 32;

    for (int i = tid; i < F_FIELDS * 13; i += 512) { sw1_s[i] = sw1[i]; sw2_s[i] = sw2[i]; }
    for (int idx = tid; idx < 32 * F_FIELDS; idx += 512) {
        int r = idx / F_FIELDS, f = idx - r * F_FIELDS;
        int id = x[(b0 + r) * F_FIELDS + f] + f * 1000;
        const float4* src = (const float4*)(emb + (size_t)id * 16);
        float4 v0 = src[0], v1 = src[1], v2 = src[2], v3 = src[3];
        int4 o0, o1;
        o0.x = (int)pk_bf16(v0.x, v0.y); o0.y = (int)pk_bf16(v0.z, v0.w);
        o0.z = (int)pk_bf16(v1.x, v1.y); o0.w = (int)pk_bf16(v1.z, v1.w);
        o1.x = (int)pk_bf16(v2.x, v2.y); o1.y = (int)pk_bf16(v2.z, v2.w);
        o1.z = (int)pk_bf16(v3.x, v3.y); o1.w = (int)pk_bf16(v3.z, v3.w);
        *(int4*)(eS + r * 424 + f * 16) = o0;
        *(int4*)(eS + r * 424 + f * 16 + 8) = o1;
        float s = v0.x + v0.y + v0.z + v0.w + v1.x + v1.y + v1.z + v1.w
                + v2.x + v2.y + v2.z + v2.w + v3.x + v3.y + v3.z + v3.w;
        z_s[r][f] = s * (1.0f / 16.0f);
    }
    __syncthreads();
    if (tid < 32) {
        float s1[13];
        #pragma unroll
        for (int o = 0; o < 13; ++o) {
            float acc0 = 0.f;
            #pragma unroll
            for (int f = 0; f < F_FIELDS; ++f) acc0 = fmaf(z_s[tid][f], sw1_s[f * 13 + o], acc0);
            s1[o] = fmaxf(acc0, 0.0f);
        }
        #pragma unroll
        for (int f = 0; f < F_FIELDS; ++f) {
            float acc0 = 0.f;
            #pragma unroll
            for (int o = 0; o < 13; ++o) acc0 = fmaf(s1[o], sw2_s[o * F_FIELDS + f], acc0);
            aS[f * 32 + tid] = fmaxf(acc0, 0.0f);
        }
    }
    __syncthreads();

    const int w    = tid >> 6;
    const int lane = tid & 63;
    const int ln   = lane & 15;
    const int q    = lane >> 4;
    const int p0 = w * 42, p1 = p0 + 42;

    f32x4 acc[2][4];
    #pragma unroll
    for (int a = 0; a < 2; ++a)
        #pragma unroll
        for (int b = 0; b < 4; ++b) acc[a][b] = (f32x4){0.f, 0.f, 0.f, 0.f};
    const f32x4 zero4 = {0.f, 0.f, 0.f, 0.f};

    int iu_c = PT.iu[p0];
    bf16x8 eiB[2];
    float ai[2];
    #pragma unroll
    for (int mt = 0; mt < 2; ++mt) {
        eiB[mt] = __builtin_bit_cast(bf16x8,
            *(const int4*)(eS + (mt * 16 + ln) * 424 + iu_c * 16 + (q & 1) * 8));
        ai[mt] = aS[iu_c * 32 + mt * 16 + ln];
    }
    bf16x8 wa_c = __builtin_bit_cast(bf16x8, *(const int4*)(wcatL + (size_t)p0 * 512 + lane * 8));
    bf16x8 wb_c[4];
    #pragma unroll
    for (int nt = 0; nt < 4; ++nt)
        wb_c[nt] = __builtin_bit_cast(bf16x8, *(const int4*)(w1catL + (size_t)p0 * 2048 + nt * 512 + lane * 8));

    #pragma unroll 2
    for (int p = p0; p < p1; ++p) {
        const int pn = (p + 1 < p1) ? (p + 1) : p;
        bf16x8 wa_n = __builtin_bit_cast(bf16x8, *(const int4*)(wcatL + (size_t)pn * 512 + lane * 8));
        bf16x8 wb_n[4];
        #pragma unroll
        for (int nt = 0; nt < 4; ++nt)
            wb_n[nt] = __builtin_bit_cast(bf16x8, *(const int4*)(w1catL + (size_t)pn * 2048 + nt * 512 + lane * 8));

        const int ju = PT.ju[p];
        uint2 ejv[2];
        float cv[2];
        #pragma unroll
        for (int mt = 0; mt < 2; ++mt) {
            ejv[mt] = *(const uint2*)(eS + (mt * 16 + ln) * 424 + ju * 16 + q * 4);
            cv[mt]  = ai[mt] * aS[ju * 32 + mt * 16 + ln];
        }
        #pragma unroll
        for (int mt = 0; mt < 2; ++mt) {
            f32x4 t = __builtin_amdgcn_mfma_f32_16x16x32_bf16(wa_c, eiB[mt], zero4, 0, 0, 0);
            float e0 = bflo(ejv[mt].x), e1 = bfhi(ejv[mt].x);
            float e2 = bflo(ejv[mt].y), e3 = bfhi(ejv[mt].y);
            float c  = cv[mt];
            float u0 = t[0] * e0, u1 = t[1] * e1, u2 = t[2] * e2, u3 = t[3] * e3;
            int4 af;
            af.x = (int)pk_trunc(u0, c * u0);
            af.y = (int)pk_trunc(u1, c * u1);
            af.z = (int)pk_trunc(u2, c * u2);
            af.w = (int)pk_trunc(u3, c * u3);
            bf16x8 A = __builtin_bit_cast(bf16x8, af);
            #pragma unroll
            for (int nt = 0; nt < 4; ++nt)
                acc[mt][nt] = __builtin_amdgcn_mfma_f32_16x16x32_bf16(A, wb_c[nt], acc[mt][nt], 0, 0, 0);
        }
        const int iu_n = PT.iu[pn];
        if (iu_n != iu_c) {
            iu_c = iu_n;
            #pragma unroll
            for (int mt = 0; mt < 2; ++mt) {
                eiB[mt] = __builtin_bit_cast(bf16x8,
                    *(const int4*)(eS + (mt * 16 + ln) * 424 + iu_c * 16 + (q & 1) * 8));
                ai[mt] = aS[iu_c * 32 + mt * 16 + ln];
            }
        }
        wa_c = wa_n;
        #pragma unroll
        for (int nt = 0; nt < 4; ++nt) wb_c[nt] = wb_n[nt];
    }

    // coalesced C-frag store: ybuf[w][mg][s=mt*2+nh][lane][4 uints]
    const size_t ub = ((size_t)w * 512 + blockIdx.x) * 1024;
    #pragma unroll
    for (int mt = 0; mt < 2; ++mt)
        #pragma unroll
        for (int nh = 0; nh < 2; ++nh) {
            int nt0 = nh * 2, nt1 = nh * 2 + 1;
            int4 v;
            v.x = (int)pk_bf16(acc[mt][nt0][0], acc[mt][nt0][1]);
            v.y = (int)pk_bf16(acc[mt][nt0][2], acc[mt][nt0][3]);
            v.z = (int)pk_bf16(acc[mt][nt1][0], acc[mt][nt1][1]);
            v.w = (int)pk_bf16(acc[mt][nt1][2], acc[mt][nt1][3]);
            *(int4*)(ybuf + ub + (mt * 2 + nh) * 256 + lane * 4) = v;
        }
}

// ---------------- K2: merge 8 packed partials + BN/ReLU MLP tail ----------------
// Thread t: lane=t&63, nh=(t>>6)&1, mt=t>>7 -> reads int4 at ub + t*4 (coalesced).
__global__ __launch_bounds__(256) void k_epi(
        const unsigned* __restrict__ ybuf,
        const float* __restrict__ b1, const float* __restrict__ g1,
        const float* __restrict__ be1, const float* __restrict__ m1,
        const float* __restrict__ v1,
        const float* __restrict__ w2, const float* __restrict__ b2,
        const float* __restrict__ g2, const float* __restrict__ be2,
        const float* __restrict__ m2, const float* __restrict__ v2,
        const float* __restrict__ w3, const float* __restrict__ b3,
        float* __restrict__ out) {
    __shared__ __align__(16) float h1s[64 * 64];
    __shared__ float h2s[64 * 36];
    const int tid = threadIdx.x;
    const int blk = blockIdx.x;          // 256 blocks, 64 rows each
    const int b0 = blk * 64;
    const int lane = tid & 63, ln = lane & 15, q = lane >> 4;
    const int nh = (tid >> 6) & 1, mt = tid >> 7;
    const int c0 = nh * 32 + ln, c1 = nh * 32 + 16 + ln;

    const float sc0 = g1[c0] * rsqrtf(v1[c0] + BN_EPS);
    const float of0 = be1[c0] + sc0 * (b1[c0] - m1[c0]);
    const float sc1 = g1[c1] * rsqrtf(v1[c1] + BN_EPS);
    const float of1 = be1[c1] + sc1 * (b1[c1] - m1[c1]);

    #pragma unroll
    for (int mg2 = 0; mg2 < 2; ++mg2) {
        const int mg = blk * 2 + mg2;
        float s8[8];
        #pragma unroll
        for (int i = 0; i < 8; ++i) s8[i] = 0.f;
        const size_t ub = (size_t)mg * 1024 + (size_t)tid * 4;
        #pragma unroll
        for (int w = 0; w < 8; ++w) {
            int4 v = *(const int4*)(ybuf + (size_t)w * 512 * 1024 + ub);
            s8[0] += bflo((unsigned)v.x); s8[1] += bfhi((unsigned)v.x);
            s8[2] += bflo((unsigned)v.y); s8[3] += bfhi((unsigned)v.y);
            s8[4] += bflo((unsigned)v.z); s8[5] += bfhi((unsigned)v.z);
            s8[6] += bflo((unsigned)v.w); s8[7] += bfhi((unsigned)v.w);
        }
        const int row0 = mg2 * 32 + mt * 16 + q * 4;
        #pragma unroll
        for (int r = 0; r < 4; ++r) {
            h1s[(row0 + r) * 64 + c0] = fmaxf(s8[r] * sc0 + of0, 0.f);
            h1s[(row0 + r) * 64 + c1] = fmaxf(s8[4 + r] * sc1 + of1, 0.f);
        }
    }
    __syncthreads();

    const int r2 = tid >> 2;
    const int og2 = (tid & 3) << 3;
    float a2[8];
    #pragma unroll
    for (int qq = 0; qq < 8; ++qq) a2[qq] = 0.f;
    #pragma unroll 8
    for (int k = 0; k < 64; ++k) {
        float hk = h1s[r2 * 64 + k];
        float4 wa = *(const float4*)(w2 + k * 32 + og2);
        float4 wb = *(const float4*)(w2 + k * 32 + og2 + 4);
        a2[0] = fmaf(hk, wa.x, a2[0]); a2[1] = fmaf(hk, wa.y, a2[1]);
        a2[2] = fmaf(hk, wa.z, a2[2]); a2[3] = fmaf(hk, wa.w, a2[3]);
        a2[4] = fmaf(hk, wb.x, a2[4]); a2[5] = fmaf(hk, wb.y, a2[5]);
        a2[6] = fmaf(hk, wb.z, a2[6]); a2[7] = fmaf(hk, wb.w, a2[7]);
    }
    #pragma unroll
    for (int qq = 0; qq < 8; ++qq) {
        int o = og2 + qq;
        float val = g2[o] * (a2[qq] + b2[o] - m2[o]) * rsqrtf(v2[o] + BN_EPS) + be2[o];
        h2s[r2 * 36 + o] = fmaxf(val, 0.f);
    }
    __syncthreads();
    if (tid < 64) {
        float sacc = b3[0];
        #pragma unroll
        for (int k = 0; k < 32; ++k) sacc = fmaf(h2s[tid * 36 + k], w3[k], sacc);
        out[b0 + tid] = 1.0f / (1.0f + expf(-sacc));
    }
}

extern "C" void kernel_launch(void* const* d_in, const int* in_sizes, int n_in,
                              void* d_out, int out_size, void* d_ws, size_t ws_size,
                              hipStream_t stream) {
    const int*   x   = (const int*)d_in[0];
    const float* emb = (const float*)d_in[1];
    const float* sw1 = (const float*)d_in[2];
    const float* sw2 = (const float*)d_in[3];
    const float* blw = (const float*)d_in[4];
    const float* w1  = (const float*)d_in[5];
    const float* b1  = (const float*)d_in[6];
    const float* g1  = (const float*)d_in[7];
    const float* be1 = (const float*)d_in[8];
    const float* m1  = (const float*)d_in[9];
    const float* v1  = (const float*)d_in[10];
    const float* w2  = (const float*)d_in[11];
    const float* b2  = (const float*)d_in[12];
    const float* g2  = (const float*)d_in[13];
    const float* be2 = (const float*)d_in[14];
    const float* m2  = (const float*)d_in[15];
    const float* v2  = (const float*)d_in[16];
    const float* w3  = (const float*)d_in[17];
    const float* b3  = (const float*)d_in[18];
    float* out = (float*)d_out;

    // ws (bytes): w1catL 1,376,256 | wcatL 344,064 | ybuf 16,777,216 -> ~18.5 MB
    char* ws = (char*)d_ws;
    unsigned short* w1catL = (unsigned short*)ws;
    unsigned short* wcatL  = (unsigned short*)(ws + 1376256);
    unsigned*       ybuf   = (unsigned*)(ws + 1720320);

    hipLaunchKernelGGL(k_wprep, dim3(PAD_PAIRS), dim3(256), 0, stream, w1, blw, w1catL, wcatL);
    hipLaunchKernelGGL(k_main,  dim3(512), dim3(512), 0, stream,
                       x, emb, sw1, sw2, w1catL, wcatL, ybuf);
    hipLaunchKernelGGL(k_epi,   dim3(256), dim3(256), 0, stream, ybuf,
                       b1, g1, be1, m1, v1, w2, b2, g2, be2, m2, v2, w3, b3, out);
}

// Round 10
// 144.749 us; speedup vs baseline: 3.0701x; 1.0400x over previous
//
#include <hip/hip_runtime.h>
#include <cstdint>
#include <cstddef>

// FiBiNET fused inference — single fused MFMA kernel + weight repack.
// R10: k_epi folded into k_main (in-LDS 8-way reduction + BN/MLP tail);
// ybuf eliminated; t-MFMA software pipeline reinstated.
// Chain: t^T = W_p^T @ e_i^T (16x16x32) lands lanes at the y-MFMA A-slot
// (m=lane&15=batch, k'=2d+{u,cu}=q*8+j). No barriers in the pair loop.
// eS in USHORT units: field f at f*16 (32 B). Row stride 424 ush.

#define F_FIELDS 26
#define P_PAIRS 325
#define PAD_PAIRS 336
#define BATCH 16384
#define BN_EPS 1e-3f

typedef short bf16x8 __attribute__((ext_vector_type(8)));
typedef float f32x4 __attribute__((ext_vector_type(4)));

struct PairTab { unsigned char iu[PAD_PAIRS]; unsigned char ju[PAD_PAIRS]; };
static constexpr PairTab make_pairs() {
    PairTab t{};
    int p = 0;
    for (int a = 0; a < F_FIELDS; ++a)
        for (int b = a + 1; b < F_FIELDS; ++b) { t.iu[p] = (unsigned char)a; t.ju[p] = (unsigned char)b; ++p; }
    for (; p < PAD_PAIRS; ++p) { t.iu[p] = 0; t.ju[p] = 0; }
    return t;
}
__constant__ PairTab PT = make_pairs();

__device__ __forceinline__ unsigned short bf16u(float v) {
    unsigned u = __float_as_uint(v);
    unsigned r = (u + 0x7fffu + ((u >> 16) & 1u)) >> 16;
    return (unsigned short)r;
}
__device__ __forceinline__ unsigned pk_bf16(float lo, float hi) {
    return (unsigned)bf16u(lo) | ((unsigned)bf16u(hi) << 16);
}
__device__ __forceinline__ float bflo(unsigned d) { return __uint_as_float(d << 16); }
__device__ __forceinline__ float bfhi(unsigned d) { return __uint_as_float(d & 0xffff0000u); }
__device__ __forceinline__ unsigned pk_trunc(float u, float cu) {
    return __builtin_amdgcn_perm(__float_as_uint(cu), __float_as_uint(u), 0x07060302u);
}

// ---------------- K0: weight repack into lane-contiguous frag layouts ----------
__global__ __launch_bounds__(256) void k_wprep(const float* __restrict__ w1,
        const float* __restrict__ blw, unsigned short* __restrict__ w1catL,
        unsigned short* __restrict__ wcatL) {
    const int p = blockIdx.x;
    const int tid = threadIdx.x;
    if (p >= P_PAIRS) {
        int4 z = make_int4(0, 0, 0, 0);
        *(int4*)(w1catL + (size_t)p * 2048 + tid * 8) = z;
        if (tid < 64) *(int4*)(wcatL + (size_t)p * 512 + tid * 8) = z;
        return;
    }
    __shared__ float wu[1024], wv[1024], wb[256];
    ((float4*)wu)[tid] = ((const float4*)(w1 + (size_t)p * 1024))[tid];
    ((float4*)wv)[tid] = ((const float4*)(w1 + 332800 + (size_t)p * 1024))[tid];
    if (tid < 64) ((float4*)wb)[tid] = ((const float4*)(blw + (size_t)p * 256))[tid];
    __syncthreads();
    {   // w1catL[p][nt][lane][8]: element [o=nt*16+ln][k'=q*8+j], k'=2d+su
        int nt = tid >> 6, lane = tid & 63, ln = lane & 15, q = lane >> 4;
        int o = nt * 16 + ln;
        unsigned short outv[8];
        #pragma unroll
        for (int j = 0; j < 8; ++j) {
            int k = q * 8 + j, d = k >> 1, su = k & 1;
            outv[j] = bf16u(su ? wv[d * 64 + o] : wu[d * 64 + o]);
        }
        *(int4*)(w1catL + (size_t)p * 2048 + tid * 8) = *(const int4*)outv;
    }
    if (tid < 64) {  // wcatL[p][lane][8]: element [dout=ln][din=q*8+j], pad din>=16
        int ln = tid & 15, q = tid >> 4;
        unsigned short outv[8];
        #pragma unroll
        for (int j = 0; j < 8; ++j) {
            int din = q * 8 + j;
            outv[j] = (din < 16) ? bf16u(wb[din * 16 + ln]) : (unsigned short)0;
        }
        *(int4*)(wcatL + (size_t)p * 512 + tid * 8) = *(const int4*)outv;
    }
}

// LDS union: phase A (gather + pair loop) vs phase B (reduce + MLP tail)
union __align__(16) SMem {
    struct {
        unsigned short eS[32 * 424];   // 27136 B
        float aS[F_FIELDS * 32];       //  3328 B
    } a;                               // 30464 B
    struct {
        unsigned ysh[8 * 4 * 64 * 4];  // 16384 B  [w][s][lane][4]
        float h1s[32 * 65];            //  8320 B  (pad 65 breaks conflicts)
        float h2s[32 * 36];            //  4608 B
    } b;                               // 29312 B
};

// ---------------- K1: fully fused gather+SE+bilinear+GEMM+MLP ----------------
// grid 512 blocks x 512 thr (8 waves). Block owns 32 batch rows (2 m-tiles);
// wave w owns pairs [42w, 42w+42); epilogue reduces the 8 chunk-partials in
// LDS and runs BN1/ReLU -> w2 -> BN2/ReLU -> w3 -> sigmoid in-block.
__global__ __launch_bounds__(512, 4) void k_main(const int* __restrict__ x,
        const float* __restrict__ emb, const float* __restrict__ sw1,
        const float* __restrict__ sw2, const unsigned short* __restrict__ w1catL,
        const unsigned short* __restrict__ wcatL,
        const float* __restrict__ b1, const float* __restrict__ g1,
        const float* __restrict__ be1, const float* __restrict__ m1,
        const float* __restrict__ v1,
        const float* __restrict__ w2, const float* __restrict__ b2,
        const float* __restrict__ g2, const float* __restrict__ be2,
        const float* __restrict__ m2, const float* __restrict__ v2,
        const float* __restrict__ w3, const float* __restrict__ b3,
        float* __restrict__ out) {
    __shared__ SMem sm;
    __shared__ float z_s[32][F_FIELDS];
    __shared__ float sw1_s[F_FIELDS * 13];
    __shared__ float sw2_s[13 * F_FIELDS];
    const int tid = threadIdx.x;
    const int b0 = blockIdx.x * 32;
    unsigned short* eS = sm.a.eS;
    float* aS = sm.a.aS;

    for (int i = tid; i < F_FIELDS * 13; i += 512) { sw1_s[i] = sw1[i]; sw2_s[i] = sw2[i]; }
    for (int idx = tid; idx < 32 * F_FIELDS; idx += 512) {
        int r = idx / F_FIELDS, f = idx - r * F_FIELDS;
        int id = x[(b0 + r) * F_FIELDS + f] + f * 1000;
        const float4* src = (const float4*)(emb + (size_t)id * 16);
        float4 v0 = src[0], v1l = src[1], v2l = src[2], v3l = src[3];
        int4 o0, o1;
        o0.x = (int)pk_bf16(v0.x, v0.y);  o0.y = (int)pk_bf16(v0.z, v0.w);
        o0.z = (int)pk_bf16(v1l.x, v1l.y); o0.w = (int)pk_bf16(v1l.z, v1l.w);
        o1.x = (int)pk_bf16(v2l.x, v2l.y); o1.y = (int)pk_bf16(v2l.z, v2l.w);
        o1.z = (int)pk_bf16(v3l.x, v3l.y); o1.w = (int)pk_bf16(v3l.z, v3l.w);
        *(int4*)(eS + r * 424 + f * 16) = o0;
        *(int4*)(eS + r * 424 + f * 16 + 8) = o1;
        float s = v0.x + v0.y + v0.z + v0.w + v1l.x + v1l.y + v1l.z + v1l.w
                + v2l.x + v2l.y + v2l.z + v2l.w + v3l.x + v3l.y + v3l.z + v3l.w;
        z_s[r][f] = s * (1.0f / 16.0f);
    }
    __syncthreads();
    if (tid < 32) {
        float s1[13];
        #pragma unroll
        for (int o = 0; o < 13; ++o) {
            float acc0 = 0.f;
            #pragma unroll
            for (int f = 0; f < F_FIELDS; ++f) acc0 = fmaf(z_s[tid][f], sw1_s[f * 13 + o], acc0);
            s1[o] = fmaxf(acc0, 0.0f);
        }
        #pragma unroll
        for (int f = 0; f < F_FIELDS; ++f) {
            float acc0 = 0.f;
            #pragma unroll
            for (int o = 0; o < 13; ++o) acc0 = fmaf(s1[o], sw2_s[o * F_FIELDS + f], acc0);
            aS[f * 32 + tid] = fmaxf(acc0, 0.0f);
        }
    }
    __syncthreads();

    const int w    = tid >> 6;
    const int lane = tid & 63;
    const int ln   = lane & 15;
    const int q    = lane >> 4;
    const int p0 = w * 42, p1 = p0 + 42;

    f32x4 acc[2][4];
    #pragma unroll
    for (int a = 0; a < 2; ++a)
        #pragma unroll
        for (int b = 0; b < 4; ++b) acc[a][b] = (f32x4){0.f, 0.f, 0.f, 0.f};
    const f32x4 zero4 = {0.f, 0.f, 0.f, 0.f};

    int iu_c = PT.iu[p0];
    bf16x8 eiB[2];
    float ai[2];
    #pragma unroll
    for (int mt = 0; mt < 2; ++mt) {
        eiB[mt] = __builtin_bit_cast(bf16x8,
            *(const int4*)(eS + (mt * 16 + ln) * 424 + iu_c * 16 + (q & 1) * 8));
        ai[mt] = aS[iu_c * 32 + mt * 16 + ln];
    }
    bf16x8 wa_c = __builtin_bit_cast(bf16x8, *(const int4*)(wcatL + (size_t)p0 * 512 + lane * 8));
    bf16x8 wb_c[4];
    #pragma unroll
    for (int nt = 0; nt < 4; ++nt)
        wb_c[nt] = __builtin_bit_cast(bf16x8, *(const int4*)(w1catL + (size_t)p0 * 2048 + nt * 512 + lane * 8));
    f32x4 tc[2];
    #pragma unroll
    for (int mt = 0; mt < 2; ++mt)
        tc[mt] = __builtin_amdgcn_mfma_f32_16x16x32_bf16(wa_c, eiB[mt], zero4, 0, 0, 0);

    #pragma unroll 2
    for (int p = p0; p < p1; ++p) {
        const int pn = (p + 1 < p1) ? (p + 1) : p;
        bf16x8 wa_n = __builtin_bit_cast(bf16x8, *(const int4*)(wcatL + (size_t)pn * 512 + lane * 8));
        bf16x8 wb_n[4];
        #pragma unroll
        for (int nt = 0; nt < 4; ++nt)
            wb_n[nt] = __builtin_bit_cast(bf16x8, *(const int4*)(w1catL + (size_t)pn * 2048 + nt * 512 + lane * 8));

        const int ju = PT.ju[p];
        uint2 ejv[2];
        float cv[2];
        #pragma unroll
        for (int mt = 0; mt < 2; ++mt) {
            ejv[mt] = *(const uint2*)(eS + (mt * 16 + ln) * 424 + ju * 16 + q * 4);
            cv[mt]  = ai[mt] * aS[ju * 32 + mt * 16 + ln];
        }
        // advance e_i frags if next pair has a new i, then pipeline t for pn
        const int iu_n = PT.iu[pn];
        if (iu_n != iu_c) {
            iu_c = iu_n;
            #pragma unroll
            for (int mt = 0; mt < 2; ++mt) {
                eiB[mt] = __builtin_bit_cast(bf16x8,
                    *(const int4*)(eS + (mt * 16 + ln) * 424 + iu_c * 16 + (q & 1) * 8));
                ai[mt] = aS[iu_c * 32 + mt * 16 + ln];
            }
        }
        f32x4 tn[2];
        #pragma unroll
        for (int mt = 0; mt < 2; ++mt)
            tn[mt] = __builtin_amdgcn_mfma_f32_16x16x32_bf16(wa_n, eiB[mt], zero4, 0, 0, 0);

        #pragma unroll
        for (int mt = 0; mt < 2; ++mt) {
            f32x4 t = tc[mt];
            float e0 = bflo(ejv[mt].x), e1 = bfhi(ejv[mt].x);
            float e2 = bflo(ejv[mt].y), e3 = bfhi(ejv[mt].y);
            float c  = cv[mt];
            float u0 = t[0] * e0, u1 = t[1] * e1, u2 = t[2] * e2, u3 = t[3] * e3;
            int4 af;
            af.x = (int)pk_trunc(u0, c * u0);
            af.y = (int)pk_trunc(u1, c * u1);
            af.z = (int)pk_trunc(u2, c * u2);
            af.w = (int)pk_trunc(u3, c * u3);
            bf16x8 A = __builtin_bit_cast(bf16x8, af);
            #pragma unroll
            for (int nt = 0; nt < 4; ++nt)
                acc[mt][nt] = __builtin_amdgcn_mfma_f32_16x16x32_bf16(A, wb_c[nt], acc[mt][nt], 0, 0, 0);
        }
        tc[0] = tn[0]; tc[1] = tn[1];
        wa_c = wa_n;
        #pragma unroll
        for (int nt = 0; nt < 4; ++nt) wb_c[nt] = wb_n[nt];
    }

    // ---------------- fused epilogue ----------------
    __syncthreads();             // all eS/aS reads done; safe to reuse LDS
    unsigned* ysh = sm.b.ysh;
    float* h1s = sm.b.h1s;
    float* h2s = sm.b.h2s;
    #pragma unroll
    for (int mt = 0; mt < 2; ++mt)
        #pragma unroll
        for (int nh = 0; nh < 2; ++nh) {
            int nt0 = nh * 2, nt1 = nh * 2 + 1;
            int4 v;
            v.x = (int)pk_bf16(acc[mt][nt0][0], acc[mt][nt0][1]);
            v.y = (int)pk_bf16(acc[mt][nt0][2], acc[mt][nt0][3]);
            v.z = (int)pk_bf16(acc[mt][nt1][0], acc[mt][nt1][1]);
            v.w = (int)pk_bf16(acc[mt][nt1][2], acc[mt][nt1][3]);
            *(int4*)(ysh + ((w * 4 + mt * 2 + nh) * 64 + lane) * 4) = v;
        }
    __syncthreads();

    if (tid < 256) {
        const int s = tid >> 6, lane2 = tid & 63, ln2 = lane2 & 15, q2 = lane2 >> 4;
        const int mt = s >> 1, nh = s & 1;
        const int c0 = nh * 32 + ln2, c1 = c0 + 16;
        const float sc0 = g1[c0] * rsqrtf(v1[c0] + BN_EPS);
        const float of0 = be1[c0] + sc0 * (b1[c0] - m1[c0]);
        const float sc1 = g1[c1] * rsqrtf(v1[c1] + BN_EPS);
        const float of1 = be1[c1] + sc1 * (b1[c1] - m1[c1]);
        float s8[8];
        #pragma unroll
        for (int i = 0; i < 8; ++i) s8[i] = 0.f;
        #pragma unroll
        for (int wv = 0; wv < 8; ++wv) {
            int4 v = *(const int4*)(ysh + ((wv * 4 + s) * 64 + lane2) * 4);
            s8[0] += bflo((unsigned)v.x); s8[1] += bfhi((unsigned)v.x);
            s8[2] += bflo((unsigned)v.y); s8[3] += bfhi((unsigned)v.y);
            s8[4] += bflo((unsigned)v.z); s8[5] += bfhi((unsigned)v.z);
            s8[6] += bflo((unsigned)v.w); s8[7] += bfhi((unsigned)v.w);
        }
        const int row0 = mt * 16 + q2 * 4;
        #pragma unroll
        for (int r = 0; r < 4; ++r) {
            h1s[(row0 + r) * 65 + c0] = fmaxf(s8[r] * sc0 + of0, 0.f);
            h1s[(row0 + r) * 65 + c1] = fmaxf(s8[4 + r] * sc1 + of1, 0.f);
        }
    }
    __syncthreads();

    {   // w2 GEMM: row = tid>>4 (0..31), 2 outputs per thread
        const int row = tid >> 4, gg = tid & 15;
        const int o0 = gg * 2, o1 = o0 + 1;
        float a0 = 0.f, a1 = 0.f;
        #pragma unroll 8
        for (int k = 0; k < 64; ++k) {
            float hk = h1s[row * 65 + k];
            float2 wv = *(const float2*)(w2 + k * 32 + o0);
            a0 = fmaf(hk, wv.x, a0);
            a1 = fmaf(hk, wv.y, a1);
        }
        float val0 = g2[o0] * (a0 + b2[o0] - m2[o0]) * rsqrtf(v2[o0] + BN_EPS) + be2[o0];
        float val1 = g2[o1] * (a1 + b2[o1] - m2[o1]) * rsqrtf(v2[o1] + BN_EPS) + be2[o1];
        h2s[row * 36 + o0] = fmaxf(val0, 0.f);
        h2s[row * 36 + o1] = fmaxf(val1, 0.f);
    }
    __syncthreads();
    if (tid < 32) {
        float sacc = b3[0];
        #pragma unroll
        for (int k = 0; k < 32; ++k) sacc = fmaf(h2s[tid * 36 + k], w3[k], sacc);
        out[b0 + tid] = 1.0f / (1.0f + expf(-sacc));
    }
}

extern "C" void kernel_launch(void* const* d_in, const int* in_sizes, int n_in,
                              void* d_out, int out_size, void* d_ws, size_t ws_size,
                              hipStream_t stream) {
    const int*   x   = (const int*)d_in[0];
    const float* emb = (const float*)d_in[1];
    const float* sw1 = (const float*)d_in[2];
    const float* sw2 = (const float*)d_in[3];
    const float* blw = (const float*)d_in[4];
    const float* w1  = (const float*)d_in[5];
    const float* b1  = (const float*)d_in[6];
    const float* g1  = (const float*)d_in[7];
    const float* be1 = (const float*)d_in[8];
    const float* m1  = (const float*)d_in[9];
    const float* v1  = (const float*)d_in[10];
    const float* w2  = (const float*)d_in[11];
    const float* b2  = (const float*)d_in[12];
    const float* g2  = (const float*)d_in[13];
    const float* be2 = (const float*)d_in[14];
    const float* m2  = (const float*)d_in[15];
    const float* v2  = (const float*)d_in[16];
    const float* w3  = (const float*)d_in[17];
    const float* b3  = (const float*)d_in[18];
    float* out = (float*)d_out;

    // ws (bytes): w1catL 1,376,256 | wcatL 344,064 -> 1.72 MB
    char* ws = (char*)d_ws;
    unsigned short* w1catL = (unsigned short*)ws;
    unsigned short* wcatL  = (unsigned short*)(ws + 1376256);

    hipLaunchKernelGGL(k_wprep, dim3(PAD_PAIRS), dim3(256), 0, stream, w1, blw, w1catL, wcatL);
    hipLaunchKernelGGL(k_main,  dim3(512), dim3(512), 0, stream,
                       x, emb, sw1, sw2, w1catL, wcatL,
                       b1, g1, be1, m1, v1, w2, b2, g2, be2, m2, v2, w3, b3, out);
}